// Round 3
// baseline (336.148 us; speedup 1.0000x reference)
//
#include <hip/hip_runtime.h>
#include <hip/hip_bf16.h>

typedef __attribute__((ext_vector_type(8))) short bf16x8;
typedef __attribute__((ext_vector_type(4))) float f32x4;
typedef __attribute__((ext_vector_type(4))) int   i32x4;
typedef __attribute__((ext_vector_type(4))) unsigned short u16x4;
typedef unsigned short u16;

#define G_ 20000
#define B_ 512

__device__ __forceinline__ u16 f2bf(float x) {
  __hip_bfloat16 h = __float2bfloat16(x);   // RTN
  return __builtin_bit_cast(u16, h);
}
__device__ __forceinline__ float bf2f(u16 u) {
  unsigned int v = ((unsigned int)u) << 16;
  return __builtin_bit_cast(float, v);
}

// async global->LDS, 16 B per lane, LDS dest wave-uniform base + lane*16
__device__ __forceinline__ void glds16(const void* g, void* l) {
  __builtin_amdgcn_global_load_lds(
      (const __attribute__((address_space(1))) void*)g,
      (__attribute__((address_space(3))) void*)l, 16, 0, 0);
}

// swizzled u16 index for logical (row b, col kk in [0,64)) within a slab:
// 16-B chunk c stored at c ^ (b&7)
__device__ __forceinline__ int swz(int b, int kk) {
  return b * 64 + ((((kk >> 3) & 7) ^ (b & 7)) << 3) + (kk & 7);
}

// ---------------------------------------------------------------------------
// K1: per-gene micro-MLP -> X slabs [slab][512][64] bf16, chunk-swizzled.
// blockIdx.x==79 handles the clinical columns (20000..20095, zero-padded).
// ---------------------------------------------------------------------------
__global__ void k_gene(const float* __restrict__ expr,
                       const float* __restrict__ bw1, const float* __restrict__ bb1,
                       const float* __restrict__ bw2, const float* __restrict__ bb2,
                       const float* __restrict__ gw,  const float* __restrict__ gb,
                       const int* __restrict__ cc, const float* __restrict__ cnc,
                       const float* __restrict__ race, const float* __restrict__ eth,
                       const float* __restrict__ inter, const float* __restrict__ prot,
                       const float* __restrict__ mw, const float* __restrict__ mb,
                       u16* __restrict__ Xt) {
  int b0 = blockIdx.y * 32;

  if (blockIdx.x == 79) {
    // clinical: 256 threads cover 32 b x 96 cols (12 cols per thread)
    int b = b0 + (threadIdx.x >> 3);
    int j0 = (threadIdx.x & 7) * 12;
    int c0 = cc[b * 3], c1 = cc[b * 3 + 1], c2 = cc[b * 3 + 2];
    float nc[10];
    #pragma unroll
    for (int v = 0; v < 10; ++v)
      nc[v] = fmaxf(cnc[b * 20 + v] * mw[v * 2] + cnc[b * 20 + 10 + v] * mw[v * 2 + 1] + mb[v], 0.f);
    #pragma unroll
    for (int jj = 0; jj < 12; ++jj) {
      int j = j0 + jj;
      float v;
      if (j < 8)       v = race[c0 * 8 + j];
      else if (j < 12) v = eth[c1 * 4 + (j - 8)];
      else if (j < 20) v = inter[(c0 * 4 + c1) * 8 + (j - 12)];
      else if (j < 28) v = prot[c2 * 8 + (j - 20)];
      else if (j < 38) v = nc[j - 28];
      else             v = 0.f;
      int k = 20000 + j;
      Xt[(size_t)(k >> 6) * 32768 + swz(b, k & 63)] = f2bf(v);
    }
    return;
  }

  int g = blockIdx.x * 256 + threadIdx.x;
  if (g >= G_) return;

  f32x4 w1a = ((const f32x4*)bw1)[g];
  f32x4 w1b = ((const f32x4*)bw1)[G_ + g];
  f32x4 b1a = ((const f32x4*)bb1)[g];
  f32x4 b1b = ((const f32x4*)bb1)[G_ + g];
  f32x4 w2a = ((const f32x4*)bw2)[g];
  f32x4 w2b = ((const f32x4*)bw2)[G_ + g];
  float bb2a = bb2[g], bb2b = bb2[G_ + g];
  float gw0 = gw[g * 2], gw1 = gw[g * 2 + 1];
  float gbg = gb[g];

  u16* slab = Xt + (size_t)(g >> 6) * 32768;
  int kk = g & 63, ch = (kk >> 3) & 7, klo = kk & 7;

  #pragma unroll 4
  for (int b = b0; b < b0 + 32; ++b) {
    float x0 = expr[(size_t)(b * 2) * G_ + g];
    float x1 = expr[(size_t)(b * 2 + 1) * G_ + g];
    float h0 = fmaxf(x0 * w1a.x + b1a.x, 0.f);
    float h1 = fmaxf(x0 * w1a.y + b1a.y, 0.f);
    float h2 = fmaxf(x0 * w1a.z + b1a.z, 0.f);
    float h3 = fmaxf(x0 * w1a.w + b1a.w, 0.f);
    float s0 = fmaxf(h0 * w2a.x + h1 * w2a.y + h2 * w2a.z + h3 * w2a.w + bb2a, 0.f);
    float g0 = fmaxf(x1 * w1b.x + b1b.x, 0.f);
    float g1 = fmaxf(x1 * w1b.y + b1b.y, 0.f);
    float g2 = fmaxf(x1 * w1b.z + b1b.z, 0.f);
    float g3 = fmaxf(x1 * w1b.w + b1b.w, 0.f);
    float s1 = fmaxf(g0 * w2b.x + g1 * w2b.y + g2 * w2b.z + g3 * w2b.w + bb2b, 0.f);
    float e = fmaxf(s0 * gw0 + s1 * gw1 + gbg, 0.f);
    slab[b * 64 + ((ch ^ (b & 7)) << 3) + klo] = f2bf(e);
  }
}

// ---------------------------------------------------------------------------
// GEMM: part[split] = Xslab(512x64k bf16, swizzled image) @ W(fp32->bf16)
// BM=512 BN=128 BK=64. A staged via global_load_lds (double-buffered LDS),
// W reg-staged (fp32->bf16 convert). Counted vmcnt(8), raw barriers.
// ---------------------------------------------------------------------------
__global__ __launch_bounds__(512, 2) void k_gemm(
    const u16* __restrict__ Xt, const float* __restrict__ W,
    float* __restrict__ part, int nSlabs, int Kvalid, int Nvalid, int Npad) {
  __shared__ __align__(16) u16 As[2][512 * 64];   // 2 x 64 KB (swizzled image)
  __shared__ __align__(16) u16 Bs[128 * 64];      // 16 KB, [n][k] swizzled

  const int tid = threadIdx.x;
  const int nt = blockIdx.x, split = blockIdx.y, S = gridDim.y;
  const int n0 = nt * 128;
  const int s0 = (int)(((long)split * nSlabs) / S);
  const int s1 = (int)(((long)(split + 1) * nSlabs) / S);
  const int sLast = s1 - 1;

  const int lane = tid & 63, wv = tid >> 6;
  const int wr = wv >> 1, wc = wv & 1;   // 4x2 wave grid, wave tile 128x64
  const int l15 = lane & 15, l4 = lane >> 4;
  const int bn = tid & 127, bh = tid >> 7;
  const int nW = n0 + bn;
  const bool nok = nW < Nvalid;

  f32x4 acc[8][4];
  #pragma unroll
  for (int i = 0; i < 8; ++i)
    #pragma unroll
    for (int j = 0; j < 4; ++j)
      acc[i][j] = f32x4{0.f, 0.f, 0.f, 0.f};

  float wreg[16];

  auto GLDS = [&](int s, int buf) {
    const char* sb = (const char*)(Xt + (size_t)s * 32768);
    char* lb = (char*)&As[buf][0];
    #pragma unroll
    for (int j = 0; j < 8; ++j) {
      int q = wv * 8 + j;                       // 1-KB chunk, wave-uniform
      glds16(sb + q * 1024 + lane * 16, lb + q * 1024);
    }
  };
  auto WLOAD = [&](int s) {
    int kb = s * 64 + bh * 16;
    #pragma unroll
    for (int j = 0; j < 16; ++j) {
      int k = kb + j;
      wreg[j] = (nok && k < Kvalid) ? W[(size_t)k * Nvalid + nW] : 0.f;
    }
  };
  auto BSTORE = [&]() {
    #pragma unroll
    for (int h = 0; h < 2; ++h) {
      i32x4 pk;
      #pragma unroll
      for (int q = 0; q < 4; ++q) {
        u16 lo = f2bf(wreg[h * 8 + q * 2]);
        u16 hi = f2bf(wreg[h * 8 + q * 2 + 1]);
        pk[q] = (int)(unsigned)lo | ((int)(unsigned)hi << 16);
      }
      int cch = bh * 2 + h;
      *(i32x4*)&Bs[bn * 64 + ((cch ^ (bn & 7)) << 3)] = pk;
    }
  };
  auto COMPUTE = [&](int buf) {
    #pragma unroll
    for (int kk = 0; kk < 2; ++kk) {
      bf16x8 bfr[4];
      #pragma unroll
      for (int nf = 0; nf < 4; ++nf) {
        int n = wc * 64 + nf * 16 + l15;
        int cch = kk * 4 + l4;
        bfr[nf] = *(const bf16x8*)&Bs[n * 64 + ((cch ^ (n & 7)) << 3)];
      }
      #pragma unroll
      for (int mf = 0; mf < 8; ++mf) {
        int m = wr * 128 + mf * 16 + l15;
        int cch = kk * 4 + l4;
        bf16x8 af = *(const bf16x8*)&As[buf][m * 64 + ((cch ^ (m & 7)) << 3)];
        #pragma unroll
        for (int nf = 0; nf < 4; ++nf)
          acc[mf][nf] = __builtin_amdgcn_mfma_f32_16x16x32_bf16(af, bfr[nf], acc[mf][nf], 0, 0, 0);
      }
    }
  };

  // prologue
  GLDS(s0, 0); WLOAD(s0);
  asm volatile("s_waitcnt vmcnt(0)" ::: "memory");
  BSTORE();                               // Bs = B(s0)
  int sp1 = (s0 + 1 > sLast) ? sLast : s0 + 1;
  GLDS(sp1, 1); WLOAD(sp1);               // in flight: A(s0+1) x8, W(s0+1) x16
  asm volatile("s_waitcnt lgkmcnt(0)" ::: "memory");
  __builtin_amdgcn_s_barrier();
  __builtin_amdgcn_sched_barrier(0);

  int c = 0;
  for (int s = s0; s < s1; ++s) {
    COMPUTE(c);                           // reads As[c], Bs
    __builtin_amdgcn_s_barrier();         // all waves done reading As[c], Bs
    __builtin_amdgcn_sched_barrier(0);
    int sp = (s + 2 > sLast) ? sLast : s + 2;
    GLDS(sp, c);                          // overwrite freed buffer
    // outstanding: [A(s+1) x8][W(s+1) x16][A(s+2) x8] -> retire oldest 24
    asm volatile("s_waitcnt vmcnt(8)" ::: "memory");
    BSTORE();                             // Bs = B(s+1)
    WLOAD(sp);                            // prefetch W(s+2)
    asm volatile("s_waitcnt lgkmcnt(0)" ::: "memory");
    __builtin_amdgcn_s_barrier();         // As[c^1]=A(s+1) & Bs(s+1) ready
    __builtin_amdgcn_sched_barrier(0);
    c ^= 1;
  }

  float* outp = part + (size_t)split * B_ * Npad;
  #pragma unroll
  for (int mf = 0; mf < 8; ++mf)
    #pragma unroll
    for (int nf = 0; nf < 4; ++nf) {
      int col = n0 + wc * 64 + nf * 16 + l15;
      int rb = wr * 128 + mf * 16 + l4 * 4;
      #pragma unroll
      for (int r = 0; r < 4; ++r)
        outp[(size_t)(rb + r) * Npad + col] = acc[mf][nf][r];
    }
}

// ---------------------------------------------------------------------------
// Reduce split-K partials + bias + ReLU -> bf16 swizzled slab activations
// ---------------------------------------------------------------------------
__global__ void k_reduce(const float* __restrict__ part, const float* __restrict__ bias,
                         u16* __restrict__ Ht, int S, int Npad, int Nout, int Nvalid) {
  int idx = blockIdx.x * 256 + threadIdx.x;
  int perRow = Nout >> 2;
  if (idx >= B_ * perRow) return;
  int b = idx / perRow;
  int n = (idx - b * perRow) * 4;
  float v[4] = {0.f, 0.f, 0.f, 0.f};
  for (int s = 0; s < S; ++s) {
    const f32x4 p = *(const f32x4*)&part[(size_t)s * B_ * Npad + (size_t)b * Npad + n];
    #pragma unroll
    for (int r = 0; r < 4; ++r) v[r] += p[r];
  }
  u16x4 o;
  #pragma unroll
  for (int r = 0; r < 4; ++r) {
    float bi = (n + r < Nvalid) ? bias[n + r] : 0.f;
    o[r] = f2bf(fmaxf(v[r] + bi, 0.f));
  }
  // n%4==0 -> the 4 elems stay inside one 8-elem chunk (kk&7 in {0,4})
  *(u16x4*)&Ht[(size_t)(n >> 6) * 32768 + swz(b, n & 63)] = o;
}

// ---------------------------------------------------------------------------
// Tail: layers 3 (313->78) and 4 (78->2), fp32, one block per batch row
// ---------------------------------------------------------------------------
__global__ void k_tail(const u16* __restrict__ H3t,
                       const float* __restrict__ W3, const float* __restrict__ b3,
                       const float* __restrict__ W4, const float* __restrict__ b4,
                       float* __restrict__ out) {
  __shared__ float h3[320];
  __shared__ float h4[80];
  int b = blockIdx.x, tid = threadIdx.x;  // 128 threads
  for (int i = tid; i < 313; i += 128)
    h3[i] = bf2f(H3t[(size_t)(i >> 6) * 32768 + swz(b, i & 63)]);
  __syncthreads();
  if (tid < 78) {
    float a = b3[tid];
    #pragma unroll 4
    for (int k = 0; k < 313; ++k) a += h3[k] * W3[k * 78 + tid];
    h4[tid] = fmaxf(a, 0.f);
  }
  __syncthreads();
  if (tid < 2) {
    float a = b4[tid];
    for (int k = 0; k < 78; ++k) a += h4[k] * W4[k * 2 + tid];
    out[b * 2 + tid] = a;
  }
}

// ---------------------------------------------------------------------------
extern "C" void kernel_launch(void* const* d_in, const int* in_sizes, int n_in,
                              void* d_out, int out_size, void* d_ws, size_t ws_size,
                              hipStream_t stream) {
  const float* expr = (const float*)d_in[0];
  const int*   cc   = (const int*)d_in[1];
  const float* cnc  = (const float*)d_in[2];
  const float* bw1  = (const float*)d_in[3];
  const float* bb1  = (const float*)d_in[4];
  const float* bw2  = (const float*)d_in[5];
  const float* bb2  = (const float*)d_in[6];
  const float* gw   = (const float*)d_in[7];
  const float* gb   = (const float*)d_in[8];
  const float* race = (const float*)d_in[9];
  const float* eth  = (const float*)d_in[10];
  const float* inter= (const float*)d_in[11];
  const float* prot = (const float*)d_in[12];
  const float* mw   = (const float*)d_in[13];
  const float* mb   = (const float*)d_in[14];
  const float* w0 = (const float*)d_in[15]; const float* b0 = (const float*)d_in[16];
  const float* w1 = (const float*)d_in[17]; const float* b1 = (const float*)d_in[18];
  const float* w2 = (const float*)d_in[19]; const float* b2 = (const float*)d_in[20];
  const float* w3 = (const float*)d_in[21]; const float* b3 = (const float*)d_in[22];
  const float* w4 = (const float*)d_in[23]; const float* b4 = (const float*)d_in[24];

  // workspace: Xt 314 slabs | H1t 80 | H2t 20 | H3t 5 | part (fp32, 63 MB max)
  u16* Xt  = (u16*)d_ws;
  u16* H1t = Xt  + (size_t)314 * 32768;
  u16* H2t = H1t + (size_t)80 * 32768;
  u16* H3t = H2t + (size_t)20 * 32768;
  float* part = (float*)(H3t + (size_t)5 * 32768);

  // gene micro-MLP + clinical (fused) -> swizzled X slabs
  k_gene<<<dim3(80, 16), 256, 0, stream>>>(expr, bw1, bb1, bw2, bb2, gw, gb,
                                           cc, cnc, race, eth, inter, prot, mw, mb, Xt);

  // L0: (512 x 20038) @ (20038 x 5009), 314 slabs, split-K=6
  k_gemm<<<dim3(40, 6), 512, 0, stream>>>(Xt, w0, part, 314, 20038, 5009, 5120);
  k_reduce<<<2560, 256, 0, stream>>>(part, b0, H1t, 6, 5120, 5120, 5009);

  // L1: (512 x 5009) @ (5009 x 1252), 80 slabs, split-K=12
  k_gemm<<<dim3(10, 12), 512, 0, stream>>>(H1t, w1, part, 80, 5009, 1252, 1280);
  k_reduce<<<640, 256, 0, stream>>>(part, b1, H2t, 12, 1280, 1280, 1252);

  // L2: (512 x 1252) @ (1252 x 313), 20 slabs, split-K=5
  k_gemm<<<dim3(3, 5), 512, 0, stream>>>(H2t, w2, part, 20, 1252, 313, 384);
  k_reduce<<<160, 256, 0, stream>>>(part, b2, H3t, 5, 384, 320, 313);

  // L3+L4 tail, fp32
  k_tail<<<512, 128, 0, stream>>>(H3t, w3, b3, w4, b4, (float*)d_out);
}

// Round 4
// 319.454 us; speedup vs baseline: 1.0523x; 1.0523x over previous
//
#include <hip/hip_runtime.h>
#include <hip/hip_bf16.h>

typedef __attribute__((ext_vector_type(8))) short bf16x8;
typedef __attribute__((ext_vector_type(4))) float f32x4;
typedef __attribute__((ext_vector_type(4))) int   i32x4;
typedef __attribute__((ext_vector_type(4))) unsigned short u16x4;
typedef unsigned short u16;

#define G_ 20000
#define B_ 512

__device__ __forceinline__ u16 f2bf(float x) {
  __hip_bfloat16 h = __float2bfloat16(x);   // RTN
  return __builtin_bit_cast(u16, h);
}
__device__ __forceinline__ float bf2f(u16 u) {
  unsigned int v = ((unsigned int)u) << 16;
  return __builtin_bit_cast(float, v);
}

// async global->LDS, 16 B per lane, LDS dest wave-uniform base + lane*16
__device__ __forceinline__ void glds16(const void* g, void* l) {
  __builtin_amdgcn_global_load_lds(
      (const __attribute__((address_space(1))) void*)g,
      (__attribute__((address_space(3))) void*)l, 16, 0, 0);
}

// swizzled u16 index for logical (row b, col kk in [0,64)) within a slab:
// 16-B chunk c stored at c ^ (b&7)
__device__ __forceinline__ int swz(int b, int kk) {
  return b * 64 + ((((kk >> 3) & 7) ^ (b & 7)) << 3) + (kk & 7);
}

// ---------------------------------------------------------------------------
// K1: per-gene micro-MLP -> X slabs [slab][512][64] bf16, chunk-swizzled.
// blockIdx.x==79 handles the clinical columns (20000..20095, zero-padded).
// ---------------------------------------------------------------------------
__global__ void k_gene(const float* __restrict__ expr,
                       const float* __restrict__ bw1, const float* __restrict__ bb1,
                       const float* __restrict__ bw2, const float* __restrict__ bb2,
                       const float* __restrict__ gw,  const float* __restrict__ gb,
                       const int* __restrict__ cc, const float* __restrict__ cnc,
                       const float* __restrict__ race, const float* __restrict__ eth,
                       const float* __restrict__ inter, const float* __restrict__ prot,
                       const float* __restrict__ mw, const float* __restrict__ mb,
                       u16* __restrict__ Xt) {
  int b0 = blockIdx.y * 32;

  if (blockIdx.x == 79) {
    int b = b0 + (threadIdx.x >> 3);
    int j0 = (threadIdx.x & 7) * 12;
    int c0 = cc[b * 3], c1 = cc[b * 3 + 1], c2 = cc[b * 3 + 2];
    float nc[10];
    #pragma unroll
    for (int v = 0; v < 10; ++v)
      nc[v] = fmaxf(cnc[b * 20 + v] * mw[v * 2] + cnc[b * 20 + 10 + v] * mw[v * 2 + 1] + mb[v], 0.f);
    #pragma unroll
    for (int jj = 0; jj < 12; ++jj) {
      int j = j0 + jj;
      float v;
      if (j < 8)       v = race[c0 * 8 + j];
      else if (j < 12) v = eth[c1 * 4 + (j - 8)];
      else if (j < 20) v = inter[(c0 * 4 + c1) * 8 + (j - 12)];
      else if (j < 28) v = prot[c2 * 8 + (j - 20)];
      else if (j < 38) v = nc[j - 28];
      else             v = 0.f;
      int k = 20000 + j;
      Xt[(size_t)(k >> 6) * 32768 + swz(b, k & 63)] = f2bf(v);
    }
    return;
  }

  int g = blockIdx.x * 256 + threadIdx.x;
  if (g >= G_) return;

  f32x4 w1a = ((const f32x4*)bw1)[g];
  f32x4 w1b = ((const f32x4*)bw1)[G_ + g];
  f32x4 b1a = ((const f32x4*)bb1)[g];
  f32x4 b1b = ((const f32x4*)bb1)[G_ + g];
  f32x4 w2a = ((const f32x4*)bw2)[g];
  f32x4 w2b = ((const f32x4*)bw2)[G_ + g];
  float bb2a = bb2[g], bb2b = bb2[G_ + g];
  float gw0 = gw[g * 2], gw1 = gw[g * 2 + 1];
  float gbg = gb[g];

  u16* slab = Xt + (size_t)(g >> 6) * 32768;
  int kk = g & 63, ch = (kk >> 3) & 7, klo = kk & 7;

  #pragma unroll 4
  for (int b = b0; b < b0 + 32; ++b) {
    float x0 = expr[(size_t)(b * 2) * G_ + g];
    float x1 = expr[(size_t)(b * 2 + 1) * G_ + g];
    float h0 = fmaxf(x0 * w1a.x + b1a.x, 0.f);
    float h1 = fmaxf(x0 * w1a.y + b1a.y, 0.f);
    float h2 = fmaxf(x0 * w1a.z + b1a.z, 0.f);
    float h3 = fmaxf(x0 * w1a.w + b1a.w, 0.f);
    float s0 = fmaxf(h0 * w2a.x + h1 * w2a.y + h2 * w2a.z + h3 * w2a.w + bb2a, 0.f);
    float g0 = fmaxf(x1 * w1b.x + b1b.x, 0.f);
    float g1 = fmaxf(x1 * w1b.y + b1b.y, 0.f);
    float g2 = fmaxf(x1 * w1b.z + b1b.z, 0.f);
    float g3 = fmaxf(x1 * w1b.w + b1b.w, 0.f);
    float s1 = fmaxf(g0 * w2b.x + g1 * w2b.y + g2 * w2b.z + g3 * w2b.w + bb2b, 0.f);
    float e = fmaxf(s0 * gw0 + s1 * gw1 + gbg, 0.f);
    slab[b * 64 + ((ch ^ (b & 7)) << 3) + klo] = f2bf(e);
  }
}

// ---------------------------------------------------------------------------
// GEMM: BM=512 BN=64 BK=64, 8 waves (wave-tile 64x64), 72 KB LDS -> 2 blk/CU.
// A via global_load_lds (single-buffered, producer-swizzled image);
// W reg-prefetched one slab ahead; counted vmcnt(8); raw barriers; no pinning.
// ---------------------------------------------------------------------------
__global__ __launch_bounds__(512, 4) void k_gemm(
    const u16* __restrict__ Xt, const float* __restrict__ W,
    float* __restrict__ part, int nSlabs, int Kvalid, int Nvalid, int Npad) {
  __shared__ __align__(16) u16 As[512 * 64];   // 64 KB (swizzled image)
  __shared__ __align__(16) u16 Bs[64 * 64];    // 8 KB, [n][k] swizzled

  const int tid = threadIdx.x;
  const int nt = blockIdx.x, split = blockIdx.y, S = gridDim.y;
  const int n0 = nt * 64;
  const int s0 = (int)(((long)split * nSlabs) / S);
  const int s1 = (int)(((long)(split + 1) * nSlabs) / S);
  const int sLast = s1 - 1;

  const int lane = tid & 63, wv = tid >> 6;
  const int l15 = lane & 15, l4 = lane >> 4;
  const int bn = lane;                 // B staging: col (consecutive in wave)
  const int bh = wv;                   // k-octant
  const int nW = n0 + bn;
  const bool nok = nW < Nvalid;

  f32x4 acc[4][4];
  #pragma unroll
  for (int i = 0; i < 4; ++i)
    #pragma unroll
    for (int j = 0; j < 4; ++j)
      acc[i][j] = f32x4{0.f, 0.f, 0.f, 0.f};

  float wreg[8];

  auto GLDS = [&](int s) {
    const char* sb = (const char*)(Xt + (size_t)s * 32768);
    char* lb = (char*)&As[0];
    #pragma unroll
    for (int j = 0; j < 8; ++j) {
      int q = wv * 8 + j;                       // 1-KB chunk, wave-uniform
      glds16(sb + q * 1024 + lane * 16, lb + q * 1024);
    }
  };
  auto WLOAD = [&](int s) {
    int kb = s * 64 + bh * 8;
    #pragma unroll
    for (int j = 0; j < 8; ++j) {
      int k = kb + j;
      wreg[j] = (nok && k < Kvalid) ? W[(size_t)k * Nvalid + nW] : 0.f;
    }
  };
  auto BSTORE = [&]() {
    i32x4 pk;
    #pragma unroll
    for (int q = 0; q < 4; ++q) {
      u16 lo = f2bf(wreg[q * 2]);
      u16 hi = f2bf(wreg[q * 2 + 1]);
      pk[q] = (int)(unsigned)lo | ((int)(unsigned)hi << 16);
    }
    *(i32x4*)&Bs[bn * 64 + ((bh ^ (bn & 7)) << 3)] = pk;
  };
  auto COMPUTE = [&]() {
    #pragma unroll
    for (int kk = 0; kk < 2; ++kk) {
      bf16x8 bfr[4];
      #pragma unroll
      for (int nf = 0; nf < 4; ++nf) {
        int n = nf * 16 + l15;
        int cch = kk * 4 + l4;
        bfr[nf] = *(const bf16x8*)&Bs[n * 64 + ((cch ^ (n & 7)) << 3)];
      }
      #pragma unroll
      for (int mf = 0; mf < 4; ++mf) {
        int m = wv * 64 + mf * 16 + l15;
        int cch = kk * 4 + l4;
        bf16x8 af = *(const bf16x8*)&As[m * 64 + ((cch ^ (m & 7)) << 3)];
        #pragma unroll
        for (int nf = 0; nf < 4; ++nf)
          acc[mf][nf] = __builtin_amdgcn_mfma_f32_16x16x32_bf16(af, bfr[nf], acc[mf][nf], 0, 0, 0);
      }
    }
  };

  // prologue: stage slab s0, prefetch W(s0+1)
  GLDS(s0); WLOAD(s0);
  BSTORE();                               // auto-waits W(s0) (drains glds too)
  WLOAD((s0 + 1 > sLast) ? sLast : s0 + 1);
  asm volatile("s_waitcnt vmcnt(8) lgkmcnt(0)" ::: "memory");
  __builtin_amdgcn_s_barrier();

  for (int s = s0; s < s1; ++s) {
    COMPUTE();                            // reads As(s), Bs(s)
    __builtin_amdgcn_s_barrier();         // all waves done reading
    if (s + 1 <= sLast) {
      GLDS(s + 1);                        // refill As
      BSTORE();                           // Bs(s+1) from wreg (auto-wait W(s+1))
      WLOAD((s + 2 > sLast) ? sLast : s + 2);   // stays in flight over COMPUTE
      asm volatile("s_waitcnt vmcnt(8) lgkmcnt(0)" ::: "memory");
      __builtin_amdgcn_s_barrier();       // As(s+1), Bs(s+1) ready
    }
  }

  float* outp = part + (size_t)split * B_ * Npad;
  #pragma unroll
  for (int mf = 0; mf < 4; ++mf)
    #pragma unroll
    for (int nf = 0; nf < 4; ++nf) {
      int col = n0 + nf * 16 + l15;
      int rb = wv * 64 + mf * 16 + l4 * 4;
      #pragma unroll
      for (int r = 0; r < 4; ++r)
        outp[(size_t)(rb + r) * Npad + col] = acc[mf][nf][r];
    }
}

// ---------------------------------------------------------------------------
// Reduce split-K partials + bias + ReLU -> bf16 swizzled slab activations
// ---------------------------------------------------------------------------
__global__ void k_reduce(const float* __restrict__ part, const float* __restrict__ bias,
                         u16* __restrict__ Ht, int S, int Npad, int Nout, int Nvalid) {
  int idx = blockIdx.x * 256 + threadIdx.x;
  int perRow = Nout >> 2;
  if (idx >= B_ * perRow) return;
  int b = idx / perRow;
  int n = (idx - b * perRow) * 4;
  float v[4] = {0.f, 0.f, 0.f, 0.f};
  for (int s = 0; s < S; ++s) {
    const f32x4 p = *(const f32x4*)&part[(size_t)s * B_ * Npad + (size_t)b * Npad + n];
    #pragma unroll
    for (int r = 0; r < 4; ++r) v[r] += p[r];
  }
  u16x4 o;
  #pragma unroll
  for (int r = 0; r < 4; ++r) {
    float bi = (n + r < Nvalid) ? bias[n + r] : 0.f;
    o[r] = f2bf(fmaxf(v[r] + bi, 0.f));
  }
  *(u16x4*)&Ht[(size_t)(n >> 6) * 32768 + swz(b, n & 63)] = o;
}

// ---------------------------------------------------------------------------
// Fused tail: reduce L2 partials (+bias+relu) -> L3 (313->78) -> L4 (78->2)
// one block per batch row, 128 threads
// ---------------------------------------------------------------------------
__global__ void k_tail(const float* __restrict__ part2, const float* __restrict__ b2,
                       const float* __restrict__ W3, const float* __restrict__ b3,
                       const float* __restrict__ W4, const float* __restrict__ b4,
                       int S2, int Npad2, float* __restrict__ out) {
  __shared__ float h3[320];
  __shared__ float h4[80];
  int b = blockIdx.x, tid = threadIdx.x;  // 128 threads
  for (int n = tid; n < 320; n += 128) {
    float v = 0.f;
    for (int s = 0; s < S2; ++s)
      v += part2[(size_t)s * B_ * Npad2 + (size_t)b * Npad2 + n];
    float bi = (n < 313) ? b2[n] : 0.f;
    h3[n] = fmaxf(v + bi, 0.f);
  }
  __syncthreads();
  if (tid < 78) {
    float a = b3[tid];
    #pragma unroll 4
    for (int k = 0; k < 313; ++k) a += h3[k] * W3[k * 78 + tid];
    h4[tid] = fmaxf(a, 0.f);
  }
  __syncthreads();
  if (tid < 2) {
    float a = b4[tid];
    for (int k = 0; k < 78; ++k) a += h4[k] * W4[k * 2 + tid];
    out[b * 2 + tid] = a;
  }
}

// ---------------------------------------------------------------------------
extern "C" void kernel_launch(void* const* d_in, const int* in_sizes, int n_in,
                              void* d_out, int out_size, void* d_ws, size_t ws_size,
                              hipStream_t stream) {
  const float* expr = (const float*)d_in[0];
  const int*   cc   = (const int*)d_in[1];
  const float* cnc  = (const float*)d_in[2];
  const float* bw1  = (const float*)d_in[3];
  const float* bb1  = (const float*)d_in[4];
  const float* bw2  = (const float*)d_in[5];
  const float* bb2  = (const float*)d_in[6];
  const float* gw   = (const float*)d_in[7];
  const float* gb   = (const float*)d_in[8];
  const float* race = (const float*)d_in[9];
  const float* eth  = (const float*)d_in[10];
  const float* inter= (const float*)d_in[11];
  const float* prot = (const float*)d_in[12];
  const float* mw   = (const float*)d_in[13];
  const float* mb   = (const float*)d_in[14];
  const float* w0 = (const float*)d_in[15]; const float* b0 = (const float*)d_in[16];
  const float* w1 = (const float*)d_in[17]; const float* b1 = (const float*)d_in[18];
  const float* w2 = (const float*)d_in[19]; const float* b2 = (const float*)d_in[20];
  const float* w3 = (const float*)d_in[21]; const float* b3 = (const float*)d_in[22];
  const float* w4 = (const float*)d_in[23]; const float* b4 = (const float*)d_in[24];

  // workspace: Xt 314 slabs | H1t 80 | H2t 20 | part (fp32, 63 MB max)
  u16* Xt  = (u16*)d_ws;
  u16* H1t = Xt  + (size_t)314 * 32768;
  u16* H2t = H1t + (size_t)80 * 32768;
  float* part = (float*)(H2t + (size_t)20 * 32768);

  // gene micro-MLP + clinical (fused) -> swizzled X slabs
  k_gene<<<dim3(80, 16), 256, 0, stream>>>(expr, bw1, bb1, bw2, bb2, gw, gb,
                                           cc, cnc, race, eth, inter, prot, mw, mb, Xt);

  // L0: (512 x 20038) @ (20038 x 5009), 314 slabs, BN=64, split-K=6 -> 480 blocks
  k_gemm<<<dim3(80, 6), 512, 0, stream>>>(Xt, w0, part, 314, 20038, 5009, 5120);
  k_reduce<<<2560, 256, 0, stream>>>(part, b0, H1t, 6, 5120, 5120, 5009);

  // L1: (512 x 5009) @ (5009 x 1252), 80 slabs, BN=64, split-K=8 -> 160 blocks
  k_gemm<<<dim3(20, 8), 512, 0, stream>>>(H1t, w1, part, 80, 5009, 1252, 1280);
  k_reduce<<<640, 256, 0, stream>>>(part, b1, H2t, 8, 1280, 1280, 1252);

  // L2: (512 x 1252) @ (1252 x 313), 20 slabs, BN=64, split-K=5 -> 30 blocks
  k_gemm<<<dim3(6, 5), 512, 0, stream>>>(H2t, w2, part, 20, 1252, 313, 384);

  // fused reduce(L2) + L3 + L4 tail
  k_tail<<<512, 128, 0, stream>>>(part, b2, w3, b3, w4, b4, 5, 384, (float*)d_out);
}